// Round 2
// baseline (2669.174 us; speedup 1.0000x reference)
//
#include <hip/hip_runtime.h>

// Elman RNN on MI355X. B=64, T=2048, D=H=256.
// Kernel 1: px = xs @ W_ih + b_hh  (f16 MFMA, fp32 out) written into ys region.
// Kernel 2: sequential scan, 4 blocks x 16 rows, 4 waves/block (1/SIMD), each
//           wave owns 64 cols. W_hh resident in VGPRs (128/lane). h exchanged
//           through XOR-swizzled ping-pong LDS. ys overwritten in place.

typedef _Float16 half8 __attribute__((ext_vector_type(8)));
typedef float floatx4 __attribute__((ext_vector_type(4)));
typedef float f32x4 __attribute__((ext_vector_type(4)));

constexpr int Bb = 64, Tt = 2048, Dd = 256, Hh = 256;

// LDS address for h[row][col] (f16). 16B blocks along col; block index XORed
// with (row&7) ^ (row&8): keeps 8-lane b128 read phases conflict-free AND
// separates the (q, q+2) row pairs on the b16 epilogue writes.
__device__ __forceinline__ int lds_addr(int row, int col) {
    const int blk = ((col >> 3) ^ (row & 7) ^ (row & 8)) & 31;
    return row * 512 + (blk << 4) + ((col & 7) << 1);
}

__device__ __forceinline__ float fast_tanh(float x) {
    float e = __builtin_amdgcn_exp2f(x * 2.885390081777927f);
    float r = __builtin_amdgcn_rcpf(e + 1.0f);
    return __builtin_fmaf(-2.0f, r, 1.0f);
}

// ---------------------------------------------------------------------------
// Kernel 1: px[b*T+t][n] = xs[b*T+t][:] @ W_ih[:,n] + b_hh[n]   (unchanged)
// ---------------------------------------------------------------------------
__global__ __launch_bounds__(256, 2) void px_gemm(const float* __restrict__ xs,
                                                  const float* __restrict__ Wih,
                                                  const float* __restrict__ bhh,
                                                  float* __restrict__ px) {
    const int lane = threadIdx.x & 63;
    const int w = threadIdx.x >> 6;
    const int q = lane >> 4;
    const int m = lane & 15;

    half8 bf[4][8];
#pragma unroll
    for (int tt = 0; tt < 4; ++tt) {
        const int n = 64 * w + 16 * tt + m;
#pragma unroll
        for (int c = 0; c < 8; ++c) {
            half8 f;
#pragma unroll
            for (int j = 0; j < 8; ++j)
                f[j] = (_Float16)Wih[(32 * c + 8 * q + j) * Hh + n];
            bf[tt][c] = f;
        }
    }
    float bias[4];
#pragma unroll
    for (int tt = 0; tt < 4; ++tt) bias[tt] = bhh[64 * w + 16 * tt + m];

    for (int i = 0; i < 8; ++i) {
        const int tau = blockIdx.x * 8 + i;
        const float* arow = xs + (size_t)(tau * 16 + m) * Dd;
        half8 af[8];
#pragma unroll
        for (int c = 0; c < 8; ++c) {
            f32x4 lo = *(const f32x4*)(arow + 32 * c + 8 * q);
            f32x4 hi = *(const f32x4*)(arow + 32 * c + 8 * q + 4);
            half8 f;
            f[0] = (_Float16)lo[0]; f[1] = (_Float16)lo[1];
            f[2] = (_Float16)lo[2]; f[3] = (_Float16)lo[3];
            f[4] = (_Float16)hi[0]; f[5] = (_Float16)hi[1];
            f[6] = (_Float16)hi[2]; f[7] = (_Float16)hi[3];
            af[c] = f;
        }
        floatx4 acc[4];
#pragma unroll
        for (int tt = 0; tt < 4; ++tt) {
            acc[tt][0] = bias[tt]; acc[tt][1] = bias[tt];
            acc[tt][2] = bias[tt]; acc[tt][3] = bias[tt];
        }
#pragma unroll
        for (int c = 0; c < 8; ++c)
#pragma unroll
            for (int tt = 0; tt < 4; ++tt)
                acc[tt] = __builtin_amdgcn_mfma_f32_16x16x32_f16(af[c], bf[tt][c], acc[tt], 0, 0, 0);
#pragma unroll
        for (int tt = 0; tt < 4; ++tt)
#pragma unroll
            for (int r = 0; r < 4; ++r)
                px[(size_t)(tau * 16 + 4 * q + r) * Hh + 64 * w + 16 * tt + m] = acc[tt][r];
    }
}

// ---------------------------------------------------------------------------
// Kernel 2: scan. 4 blocks x 256 thr (4 waves, 1/SIMD). Wave w: cols [64w,64w+64).
// Unrolled x2 (ping-pong LDS via static offsets, two px register sets,
// prefetch distance 2). One barrier per step.
// ---------------------------------------------------------------------------
__global__ __launch_bounds__(256, 1) void rnn_scan(const float* __restrict__ c0,
                                                   const float* __restrict__ Whh,
                                                   float* __restrict__ hfin,
                                                   float* __restrict__ ys) {
    __shared__ alignas(16) unsigned char hb[2][8192];
    char* const L = (char*)&hb[0][0];
    const int g = blockIdx.x;
    const int lane = threadIdx.x & 63;
    const int w = threadIdx.x >> 6;   // 0..3
    const int q = lane >> 4;
    const int m = lane & 15;

    // W_hh B fragments: 4 n-tiles x 8 k-chunks (one-time scattered loads).
    half8 bf[4][8];
#pragma unroll
    for (int tt = 0; tt < 4; ++tt) {
        const int n = 64 * w + 16 * tt + m;
#pragma unroll
        for (int c = 0; c < 8; ++c) {
            half8 f;
#pragma unroll
            for (int j = 0; j < 8; ++j)
                f[j] = (_Float16)Whh[(32 * c + 8 * q + j) * Hh + n];
            bf[tt][c] = f;
        }
    }

    // h_0 -> LDS buffer 0.
    for (int i = threadIdx.x; i < 16 * 256; i += 256) {
        const int row = i >> 8, col = i & 255;
        *(_Float16*)&L[lds_addr(row, col)] = (_Float16)c0[(16 * g + row) * Hh + col];
    }

    // Loop-invariant LDS addresses.
    int ra[8];                       // A-fragment reads: row=m, col0=32c+8q
#pragma unroll
    for (int c = 0; c < 8; ++c)
        ra[c] = m * 512 + (((((4 * c + q)) ^ (m & 7) ^ (m & 8)) & 31) << 4);
    int wa[16];                      // h writes: row=4q+r, col=64w+16tt+m
#pragma unroll
    for (int tt = 0; tt < 4; ++tt)
#pragma unroll
        for (int r = 0; r < 4; ++r)
            wa[4 * tt + r] = lds_addr(4 * q + r, 64 * w + 16 * tt + m);

    // Per-row global pointers (advanced by 256 floats per step, 512 per pair).
    const float* pr[4];
#pragma unroll
    for (int r = 0; r < 4; ++r)
        pr[r] = ys + (size_t)(16 * g + 4 * q + r) * Tt * Hh + 64 * w + m;

    // Prime px[0], px[1].
    floatx4 s0[4], s1[4];
#pragma unroll
    for (int tt = 0; tt < 4; ++tt)
#pragma unroll
        for (int r = 0; r < 4; ++r) {
            s0[tt][r] = pr[r][16 * tt];
            s1[tt][r] = pr[r][256 + 16 * tt];
        }
#pragma unroll
    for (int r = 0; r < 4; ++r) pr[r] += 512;   // now at t+2

    __syncthreads();

    for (int t = 0; t < Tt; t += 2) {
        // ---- even step t: read buf0, write buf1, consume s0, prefetch t+2 ----
        {
            half8 af[8];
#pragma unroll
            for (int c = 0; c < 8; ++c)
                af[c] = *(const half8*)(L + ra[c]);
            floatx4 acc[4];
#pragma unroll
            for (int tt = 0; tt < 4; ++tt)
                acc[tt] = __builtin_amdgcn_mfma_f32_16x16x32_f16(af[0], bf[tt][0], s0[tt], 0, 0, 0);
            if (t + 2 < Tt) {
#pragma unroll
                for (int tt = 0; tt < 4; ++tt)
#pragma unroll
                    for (int r = 0; r < 4; ++r)
                        s0[tt][r] = pr[r][16 * tt];
            }
#pragma unroll
            for (int c = 1; c < 8; ++c)
#pragma unroll
                for (int tt = 0; tt < 4; ++tt)
                    acc[tt] = __builtin_amdgcn_mfma_f32_16x16x32_f16(af[c], bf[tt][c], acc[tt], 0, 0, 0);
#pragma unroll
            for (int tt = 0; tt < 4; ++tt)
#pragma unroll
                for (int r = 0; r < 4; ++r) {
                    const float h = fast_tanh(acc[tt][r]);
                    ((float*)pr[r])[16 * tt - 512] = h;           // ys[t]
                    *(_Float16*)(L + 8192 + wa[4 * tt + r]) = (_Float16)h;
                }
            __syncthreads();
        }
        // ---- odd step t+1: read buf1, write buf0, consume s1, prefetch t+3 ----
        {
            half8 af[8];
#pragma unroll
            for (int c = 0; c < 8; ++c)
                af[c] = *(const half8*)(L + 8192 + ra[c]);
            floatx4 acc[4];
#pragma unroll
            for (int tt = 0; tt < 4; ++tt)
                acc[tt] = __builtin_amdgcn_mfma_f32_16x16x32_f16(af[0], bf[tt][0], s1[tt], 0, 0, 0);
            if (t + 3 < Tt) {
#pragma unroll
                for (int tt = 0; tt < 4; ++tt)
#pragma unroll
                    for (int r = 0; r < 4; ++r)
                        s1[tt][r] = pr[r][256 + 16 * tt];
            }
#pragma unroll
            for (int c = 1; c < 8; ++c)
#pragma unroll
                for (int tt = 0; tt < 4; ++tt)
                    acc[tt] = __builtin_amdgcn_mfma_f32_16x16x32_f16(af[c], bf[tt][c], acc[tt], 0, 0, 0);
            const bool last = (t + 2 == Tt);
#pragma unroll
            for (int tt = 0; tt < 4; ++tt)
#pragma unroll
                for (int r = 0; r < 4; ++r) {
                    const float h = fast_tanh(acc[tt][r]);
                    ((float*)pr[r])[16 * tt - 256] = h;           // ys[t+1]
                    *(_Float16*)(L + wa[4 * tt + r]) = (_Float16)h;
                    if (last)
                        hfin[(16 * g + 4 * q + r) * Hh + 64 * w + 16 * tt + m] = h;
                }
#pragma unroll
            for (int r = 0; r < 4; ++r) pr[r] += 512;
            __syncthreads();
        }
    }
}

extern "C" void kernel_launch(void* const* d_in, const int* in_sizes, int n_in,
                              void* d_out, int out_size, void* d_ws, size_t ws_size,
                              hipStream_t stream) {
    const float* c0  = (const float*)d_in[0];  // [B,H]
    const float* xs  = (const float*)d_in[1];  // [B,T,D]
    const float* Wih = (const float*)d_in[2];  // [D,H]
    const float* Whh = (const float*)d_in[3];  // [H,H]
    const float* bhh = (const float*)d_in[4];  // [H]
    float* out = (float*)d_out;
    float* hfin = out;                 // [B,H]
    float* ys = out + Bb * Hh;         // [B,T,H] — also holds px between kernels

    px_gemm<<<1024, 256, 0, stream>>>(xs, Wih, bhh, ys);
    rnn_scan<<<Bb / 16, 256, 0, stream>>>(c0, Whh, hfin, ys);
}

// Round 3
// 1850.311 us; speedup vs baseline: 1.4426x; 1.4426x over previous
//
#include <hip/hip_runtime.h>

// Elman RNN on MI355X. B=64, T=2048, D=H=256.
// Kernel 1: px = xs @ W_ih + b_hh  (f16 MFMA, fp32 out) written into ys region.
// Kernel 2: scan. 4 blocks x 512 thr (8 waves = 2/SIMD for latency hiding).
//   Wave w owns 32 cols (2 n-tiles, W_hh frags in 64 VGPRs). h exchanged via
//   conflict-free XOR-swizzled ping-pong LDS. Unroll x2: prefetch distance 2,
//   px feeds the MFMA C operand directly. ys overwritten in place.

typedef _Float16 half8 __attribute__((ext_vector_type(8)));
typedef float floatx4 __attribute__((ext_vector_type(4)));
typedef float f32x4 __attribute__((ext_vector_type(4)));

constexpr int Bb = 64, Tt = 2048, Dd = 256, Hh = 256;

// LDS address for h[row][col] (f16). 16B blocks along col; block index XORed
// with (row&7)^(row&8). R2 measured SQ_LDS_BANK_CONFLICT == 0 with this map.
__device__ __forceinline__ int lds_addr(int row, int col) {
    const int blk = ((col >> 3) ^ (row & 7) ^ (row & 8)) & 31;
    return row * 512 + (blk << 4) + ((col & 7) << 1);
}

__device__ __forceinline__ float fast_tanh(float x) {
    float e = __builtin_amdgcn_exp2f(x * 2.885390081777927f);
    float r = __builtin_amdgcn_rcpf(e + 1.0f);
    return __builtin_fmaf(-2.0f, r, 1.0f);
}

// ---------------------------------------------------------------------------
// Kernel 1: px[b*T+t][n] = xs[b*T+t][:] @ W_ih[:,n] + b_hh[n]   (unchanged)
// ---------------------------------------------------------------------------
__global__ __launch_bounds__(256, 2) void px_gemm(const float* __restrict__ xs,
                                                  const float* __restrict__ Wih,
                                                  const float* __restrict__ bhh,
                                                  float* __restrict__ px) {
    const int lane = threadIdx.x & 63;
    const int w = threadIdx.x >> 6;
    const int q = lane >> 4;
    const int m = lane & 15;

    half8 bf[4][8];
#pragma unroll
    for (int tt = 0; tt < 4; ++tt) {
        const int n = 64 * w + 16 * tt + m;
#pragma unroll
        for (int c = 0; c < 8; ++c) {
            half8 f;
#pragma unroll
            for (int j = 0; j < 8; ++j)
                f[j] = (_Float16)Wih[(32 * c + 8 * q + j) * Hh + n];
            bf[tt][c] = f;
        }
    }
    float bias[4];
#pragma unroll
    for (int tt = 0; tt < 4; ++tt) bias[tt] = bhh[64 * w + 16 * tt + m];

    for (int i = 0; i < 8; ++i) {
        const int tau = blockIdx.x * 8 + i;
        const float* arow = xs + (size_t)(tau * 16 + m) * Dd;
        half8 af[8];
#pragma unroll
        for (int c = 0; c < 8; ++c) {
            f32x4 lo = *(const f32x4*)(arow + 32 * c + 8 * q);
            f32x4 hi = *(const f32x4*)(arow + 32 * c + 8 * q + 4);
            half8 f;
            f[0] = (_Float16)lo[0]; f[1] = (_Float16)lo[1];
            f[2] = (_Float16)lo[2]; f[3] = (_Float16)lo[3];
            f[4] = (_Float16)hi[0]; f[5] = (_Float16)hi[1];
            f[6] = (_Float16)hi[2]; f[7] = (_Float16)hi[3];
            af[c] = f;
        }
        floatx4 acc[4];
#pragma unroll
        for (int tt = 0; tt < 4; ++tt) {
            acc[tt][0] = bias[tt]; acc[tt][1] = bias[tt];
            acc[tt][2] = bias[tt]; acc[tt][3] = bias[tt];
        }
#pragma unroll
        for (int c = 0; c < 8; ++c)
#pragma unroll
            for (int tt = 0; tt < 4; ++tt)
                acc[tt] = __builtin_amdgcn_mfma_f32_16x16x32_f16(af[c], bf[tt][c], acc[tt], 0, 0, 0);
#pragma unroll
        for (int tt = 0; tt < 4; ++tt)
#pragma unroll
            for (int r = 0; r < 4; ++r)
                px[(size_t)(tau * 16 + 4 * q + r) * Hh + 64 * w + 16 * tt + m] = acc[tt][r];
    }
}

// ---------------------------------------------------------------------------
// Kernel 2: scan. 4 blocks x 512 thr (8 waves, 2/SIMD). Wave w: cols [32w,32w+32).
// ---------------------------------------------------------------------------
__global__ __launch_bounds__(512, 2) void rnn_scan(const float* __restrict__ c0,
                                                   const float* __restrict__ Whh,
                                                   float* __restrict__ hfin,
                                                   float* __restrict__ ys) {
    __shared__ alignas(16) unsigned char hb[2][8192];
    char* const L = (char*)&hb[0][0];
    const int g = blockIdx.x;
    const int lane = threadIdx.x & 63;
    const int w = threadIdx.x >> 6;   // 0..7
    const int q = lane >> 4;
    const int m = lane & 15;

    // W_hh B fragments: 2 n-tiles x 8 k-chunks = 64 VGPRs (one-time loads).
    half8 bf[2][8];
#pragma unroll
    for (int tt = 0; tt < 2; ++tt) {
        const int n = 32 * w + 16 * tt + m;
#pragma unroll
        for (int c = 0; c < 8; ++c) {
            half8 f;
#pragma unroll
            for (int j = 0; j < 8; ++j)
                f[j] = (_Float16)Whh[(32 * c + 8 * q + j) * Hh + n];
            bf[tt][c] = f;
        }
    }

    // h_0 -> LDS buffer 0.
    for (int i = threadIdx.x; i < 16 * 256; i += 512) {
        const int row = i >> 8, col = i & 255;
        *(_Float16*)&L[lds_addr(row, col)] = (_Float16)c0[(16 * g + row) * Hh + col];
    }

    // Loop-invariant LDS addresses.
    int ra[8];                       // A-frag reads: row=m, col block 4c+q
#pragma unroll
    for (int c = 0; c < 8; ++c)
        ra[c] = m * 512 + ((((4 * c + q) ^ (m & 7) ^ (m & 8)) & 31) << 4);
    int wa[8];                       // h writes: row=4q+r, col=32w+16tt+m
#pragma unroll
    for (int tt = 0; tt < 2; ++tt)
#pragma unroll
        for (int r = 0; r < 4; ++r)
            wa[4 * tt + r] = lds_addr(4 * q + r, 32 * w + 16 * tt + m);

    // Per-row global pointers (advanced 512 floats per unrolled pair).
    const float* pr[4];
#pragma unroll
    for (int r = 0; r < 4; ++r)
        pr[r] = ys + (size_t)(16 * g + 4 * q + r) * Tt * Hh + 32 * w + m;

    // Prime px[0], px[1].
    floatx4 s0[2], s1[2];
#pragma unroll
    for (int tt = 0; tt < 2; ++tt)
#pragma unroll
        for (int r = 0; r < 4; ++r) {
            s0[tt][r] = pr[r][16 * tt];
            s1[tt][r] = pr[r][256 + 16 * tt];
        }
#pragma unroll
    for (int r = 0; r < 4; ++r) pr[r] += 512;   // now at t+2

    __syncthreads();

    for (int t = 0; t < Tt; t += 2) {
        // ---- even step t: read buf0, write buf1, consume s0, prefetch t+2 ----
        {
            half8 af[8];
#pragma unroll
            for (int c = 0; c < 8; ++c)
                af[c] = *(const half8*)(L + ra[c]);
            floatx4 acc[2];
#pragma unroll
            for (int tt = 0; tt < 2; ++tt)
                acc[tt] = __builtin_amdgcn_mfma_f32_16x16x32_f16(af[0], bf[tt][0], s0[tt], 0, 0, 0);
            if (t + 2 < Tt) {
#pragma unroll
                for (int tt = 0; tt < 2; ++tt)
#pragma unroll
                    for (int r = 0; r < 4; ++r)
                        s0[tt][r] = pr[r][16 * tt];
            }
#pragma unroll
            for (int c = 1; c < 8; ++c)
#pragma unroll
                for (int tt = 0; tt < 2; ++tt)
                    acc[tt] = __builtin_amdgcn_mfma_f32_16x16x32_f16(af[c], bf[tt][c], acc[tt], 0, 0, 0);
#pragma unroll
            for (int tt = 0; tt < 2; ++tt)
#pragma unroll
                for (int r = 0; r < 4; ++r) {
                    const float h = fast_tanh(acc[tt][r]);
                    ((float*)pr[r])[16 * tt - 512] = h;           // ys[t]
                    *(_Float16*)(L + 8192 + wa[4 * tt + r]) = (_Float16)h;
                }
            __syncthreads();
        }
        // ---- odd step t+1: read buf1, write buf0, consume s1, prefetch t+3 ----
        {
            half8 af[8];
#pragma unroll
            for (int c = 0; c < 8; ++c)
                af[c] = *(const half8*)(L + 8192 + ra[c]);
            floatx4 acc[2];
#pragma unroll
            for (int tt = 0; tt < 2; ++tt)
                acc[tt] = __builtin_amdgcn_mfma_f32_16x16x32_f16(af[0], bf[tt][0], s1[tt], 0, 0, 0);
            if (t + 3 < Tt) {
#pragma unroll
                for (int tt = 0; tt < 2; ++tt)
#pragma unroll
                    for (int r = 0; r < 4; ++r)
                        s1[tt][r] = pr[r][256 + 16 * tt];
            }
#pragma unroll
            for (int c = 1; c < 8; ++c)
#pragma unroll
                for (int tt = 0; tt < 2; ++tt)
                    acc[tt] = __builtin_amdgcn_mfma_f32_16x16x32_f16(af[c], bf[tt][c], acc[tt], 0, 0, 0);
#pragma unroll
            for (int tt = 0; tt < 2; ++tt)
#pragma unroll
                for (int r = 0; r < 4; ++r) {
                    const float h = fast_tanh(acc[tt][r]);
                    ((float*)pr[r])[16 * tt - 256] = h;           // ys[t+1]
                    *(_Float16*)(L + wa[4 * tt + r]) = (_Float16)h;
                }
#pragma unroll
            for (int r = 0; r < 4; ++r) pr[r] += 512;
            __syncthreads();
        }
    }

    // Final carry: last step (t=2047, odd) wrote buf0; loop ended with a barrier.
    for (int i = threadIdx.x; i < 16 * 256; i += 512) {
        const int row = i >> 8, col = i & 255;
        hfin[(16 * g + row) * Hh + col] = (float)*(const _Float16*)&L[lds_addr(row, col)];
    }
}

extern "C" void kernel_launch(void* const* d_in, const int* in_sizes, int n_in,
                              void* d_out, int out_size, void* d_ws, size_t ws_size,
                              hipStream_t stream) {
    const float* c0  = (const float*)d_in[0];  // [B,H]
    const float* xs  = (const float*)d_in[1];  // [B,T,D]
    const float* Wih = (const float*)d_in[2];  // [D,H]
    const float* Whh = (const float*)d_in[3];  // [H,H]
    const float* bhh = (const float*)d_in[4];  // [H]
    float* out = (float*)d_out;
    float* hfin = out;                 // [B,H]
    float* ys = out + Bb * Hh;         // [B,T,H] — also holds px between kernels

    px_gemm<<<1024, 256, 0, stream>>>(xs, Wih, bhh, ys);
    rnn_scan<<<Bb / 16, 512, 0, stream>>>(c0, Whh, hfin, ys);
}